// Round 11
// baseline (367.177 us; speedup 1.0000x reference)
//
#include <hip/hip_runtime.h>
#include <hip/hip_bf16.h>

// ---------------------------------------------------------------------------
// AdvisorCrossAttention on MI355X (gfx950) — round 11 (resubmit of round 9:
// GPU acquisition timed out rounds 9-10; 8-phase kernel still unmeasured)
// Big GEMMs (Q-proj, V-proj, out-proj) on the 8-phase 256x256 schedule
// (m201 template class): per K-tile 4 sub-phases of
//   {ds_read subtile | stage half-tile -> bar -> lgkm0 -> setprio MFMA -> bar},
// counted vmcnt(8) once per K-tile. Swizzle (measured 0 bank conflicts) and
// bijective XCD block swizzle retained. Small/batched GEMMs keep the proven
// 2-phase 128^2 pipeline (2 blocks/CU overlaps barriers there).
// ---------------------------------------------------------------------------

typedef unsigned short u16;
typedef __attribute__((ext_vector_type(8))) short bf16x8;   // 8 bf16 = 4 VGPRs
typedef __attribute__((ext_vector_type(4))) float f32x4;    // MFMA acc
typedef __attribute__((ext_vector_type(4))) unsigned short u16x4;

__device__ __forceinline__ u16 f2bf(float f) {
    __hip_bfloat16 h = __float2bfloat16(f);
    return *reinterpret_cast<u16*>(&h);
}
__device__ __forceinline__ float bf2f(u16 u) {
    __hip_bfloat16 h;
    *reinterpret_cast<u16*>(&h) = u;
    return __bfloat162float(h);
}

__device__ __forceinline__ void gload_lds16(const u16* g, u16* l) {
    __builtin_amdgcn_global_load_lds(
        (const __attribute__((address_space(1))) void*)g,
        (__attribute__((address_space(3))) void*)l, 16, 0, 0);
}

__device__ __forceinline__ void store_c(float* p, float v) { *p = v; }
__device__ __forceinline__ void store_c(u16* p, float v)   { *p = f2bf(v); }

// ===========================================================================
// 8-phase 256x256 GEMM (batch=1): C[m,n] = sum_k A[m,k]*B[n,k]
// 8 waves (2M x 4N), per-wave 128x64 output, BK=64, LDS 128KB double-buffer.
// ===========================================================================
template <typename TC>
__global__ __launch_bounds__(512, 2) void gemm_8ph(
    const u16* __restrict__ A, const u16* __restrict__ B, TC* __restrict__ C,
    int K, int lda, int ldb, int ldc, float alpha, int gx, int q, int r)
{
    __shared__ u16 As[2][256 * 64];
    __shared__ u16 Bs[2][256 * 64];

    // T1: bijective XCD swizzle (m204)
    const int orig = blockIdx.x;
    const int xcd  = orig & 7, lo = orig >> 3;
    const int swz  = (xcd < r ? xcd * (q + 1) : r * (q + 1) + (xcd - r) * q) + lo;
    const int bx   = swz % gx;
    const int by   = swz / gx;

    const u16* Ab = A + (long)by * 256 * lda;
    const u16* Bb = B + (long)bx * 256 * ldb;

    const int tid = threadIdx.x;
    const int l   = tid & 63;
    const int wid = tid >> 6;
    const int wr  = (wid >> 2) * 128;   // wave M offset (2 groups)
    const int wc  = (wid & 3) * 64;     // wave N offset (4 groups)
    const int lr  = l & 15;
    const int shi = l >> 4;

    // stage full A (or B) K-tile: 2048 16B chunks / 512 threads = 4 loads.
    // linear LDS dest + inverse-swizzled global source (rule 21).
    auto stageA = [&](int buf, int k0) {
#pragma unroll
        for (int i = 0; i < 4; ++i) {
            const int c = tid + i * 512, row = c >> 3, p = c & 7;
            gload_lds16(Ab + (long)row * lda + k0 + ((p ^ (row & 7)) << 3),
                        &As[buf][c << 3]);
        }
    };
    auto stageB = [&](int buf, int k0) {
#pragma unroll
        for (int i = 0; i < 4; ++i) {
            const int c = tid + i * 512, row = c >> 3, p = c & 7;
            gload_lds16(Bb + (long)row * ldb + k0 + ((p ^ (row & 7)) << 3),
                        &Bs[buf][c << 3]);
        }
    };
    auto rdA = [&](int buf, int m, int ks) -> bf16x8 {
        const int row = wr + m * 16 + lr, slot = ks * 4 + shi;
        return *(const bf16x8*)&As[buf][row * 64 + ((slot ^ (row & 7)) << 3)];
    };
    auto rdB = [&](int buf, int n, int ks) -> bf16x8 {
        const int row = wc + n * 16 + lr, slot = ks * 4 + shi;
        return *(const bf16x8*)&Bs[buf][row * 64 + ((slot ^ (row & 7)) << 3)];
    };

    f32x4 acc[8][4] = {};
    const int nk = K / 64;

    // prologue: tiles 0 and 1 staged; wait tile 0 (8 of 16 loads retired)
    stageA(0, 0);  stageB(0, 0);
    stageA(1, 64); stageB(1, 64);
    asm volatile("s_waitcnt vmcnt(8)" ::: "memory");
    __builtin_amdgcn_sched_barrier(0);
    __builtin_amdgcn_s_barrier();

    for (int t = 0; t < nk; ++t) {
        const int  cur  = t & 1;
        const bool pre  = (t + 2 < nk);
        const int  k2   = (t + 2) * 64;
        bf16x8 af[4][2], bl[2][2], bh[2][2];

        // ---- phase 1: read A-low half + B-low half; MFMA (m0-3, n0-1) ----
#pragma unroll
        for (int m = 0; m < 4; ++m) { af[m][0] = rdA(cur, m, 0); af[m][1] = rdA(cur, m, 1); }
#pragma unroll
        for (int n = 0; n < 2; ++n) { bl[n][0] = rdB(cur, n, 0); bl[n][1] = rdB(cur, n, 1); }
        __builtin_amdgcn_s_barrier();
        asm volatile("s_waitcnt lgkmcnt(0)" ::: "memory");
        __builtin_amdgcn_sched_barrier(0);
        __builtin_amdgcn_s_setprio(1);
#pragma unroll
        for (int m = 0; m < 4; ++m)
#pragma unroll
            for (int n = 0; n < 2; ++n) {
                acc[m][n] = __builtin_amdgcn_mfma_f32_16x16x32_bf16(af[m][0], bl[n][0], acc[m][n], 0, 0, 0);
                acc[m][n] = __builtin_amdgcn_mfma_f32_16x16x32_bf16(af[m][1], bl[n][1], acc[m][n], 0, 0, 0);
            }
        __builtin_amdgcn_s_setprio(0);
        __builtin_amdgcn_s_barrier();

        // ---- phase 2: read B-high half; MFMA (m0-3, n2-3) ----
#pragma unroll
        for (int n = 0; n < 2; ++n) { bh[n][0] = rdB(cur, 2 + n, 0); bh[n][1] = rdB(cur, 2 + n, 1); }
        __builtin_amdgcn_s_barrier();
        asm volatile("s_waitcnt lgkmcnt(0)" ::: "memory");
        __builtin_amdgcn_sched_barrier(0);
        __builtin_amdgcn_s_setprio(1);
#pragma unroll
        for (int m = 0; m < 4; ++m)
#pragma unroll
            for (int n = 0; n < 2; ++n) {
                acc[m][2 + n] = __builtin_amdgcn_mfma_f32_16x16x32_bf16(af[m][0], bh[n][0], acc[m][2 + n], 0, 0, 0);
                acc[m][2 + n] = __builtin_amdgcn_mfma_f32_16x16x32_bf16(af[m][1], bh[n][1], acc[m][2 + n], 0, 0, 0);
            }
        __builtin_amdgcn_s_setprio(0);
        __builtin_amdgcn_s_barrier();

        // ---- phase 3: read A-high half (overwrite af); stage B(t+2) into
        //      freed B buffer (all B reads done after phase 2); MFMA (m4-7, n2-3)
#pragma unroll
        for (int m = 0; m < 4; ++m) { af[m][0] = rdA(cur, 4 + m, 0); af[m][1] = rdA(cur, 4 + m, 1); }
        if (pre) stageB(cur, k2);
        __builtin_amdgcn_s_barrier();
        asm volatile("s_waitcnt lgkmcnt(0)" ::: "memory");
        __builtin_amdgcn_sched_barrier(0);
        __builtin_amdgcn_s_setprio(1);
#pragma unroll
        for (int m = 0; m < 4; ++m)
#pragma unroll
            for (int n = 0; n < 2; ++n) {
                acc[4 + m][2 + n] = __builtin_amdgcn_mfma_f32_16x16x32_bf16(af[m][0], bh[n][0], acc[4 + m][2 + n], 0, 0, 0);
                acc[4 + m][2 + n] = __builtin_amdgcn_mfma_f32_16x16x32_bf16(af[m][1], bh[n][1], acc[4 + m][2 + n], 0, 0, 0);
            }
        __builtin_amdgcn_s_setprio(0);
        __builtin_amdgcn_s_barrier();

        // ---- phase 4: stage A(t+2) (all A reads done after phase 3);
        //      MFMA (m4-7, n0-1); counted vmcnt before tile swap ----
        if (pre) stageA(cur, k2);
        __builtin_amdgcn_s_barrier();
        __builtin_amdgcn_s_setprio(1);
#pragma unroll
        for (int m = 0; m < 4; ++m)
#pragma unroll
            for (int n = 0; n < 2; ++n) {
                acc[4 + m][n] = __builtin_amdgcn_mfma_f32_16x16x32_bf16(af[m][0], bl[n][0], acc[4 + m][n], 0, 0, 0);
                acc[4 + m][n] = __builtin_amdgcn_mfma_f32_16x16x32_bf16(af[m][1], bl[n][1], acc[4 + m][n], 0, 0, 0);
            }
        __builtin_amdgcn_s_setprio(0);
        if (pre) { asm volatile("s_waitcnt vmcnt(8)" ::: "memory"); }
        else     { asm volatile("s_waitcnt vmcnt(0)" ::: "memory"); }
        __builtin_amdgcn_sched_barrier(0);
        __builtin_amdgcn_s_barrier();
    }

    // epilogue: D mapping col = l&15, row = (l>>4)*4 + j
    const long rB = (long)by * 256 + wr + (l >> 4) * 4;
    const long cB = (long)bx * 256 + wc + lr;
#pragma unroll
    for (int m = 0; m < 8; ++m)
#pragma unroll
        for (int n = 0; n < 4; ++n)
#pragma unroll
            for (int j = 0; j < 4; ++j)
                store_c(&C[(rB + m * 16 + j) * ldc + cB + n * 16],
                        acc[m][n][j] * alpha);
}

template <typename TC>
static inline void run_gemm8(hipStream_t s, const u16* A, const u16* B, TC* C,
                             int M, int N, int K, int lda, int ldb, int ldc,
                             float alpha)
{
    const int gx = N / 256, nwg = gx * (M / 256);
    gemm_8ph<TC><<<nwg, 512, 0, s>>>(A, B, C, K, lda, ldb, ldc, alpha,
                                     gx, nwg / 8, nwg % 8);
}

// ===========================================================================
// 2-phase 128x128 pipelined GEMM (4 waves) — measured: 0 bank conflicts.
// Used for small/batched GEMMs where 2 blocks/CU overlap the barriers.
// ===========================================================================
template <int BM, int BN, int WM, int WN, typename TC>
__global__ __launch_bounds__(WM*WN*64, 2) void gemm_pipe(
    const u16* __restrict__ A, const u16* __restrict__ B, TC* __restrict__ C,
    int K, int lda, int ldb, int ldc,
    long sA, long sB, long sC, float alpha,
    int gx, int gy, int q, int r)
{
    constexpr int NT   = WM * WN * 64;
    constexpr int MREP = BM / (WM * 16);
    constexpr int NREP = BN / (WN * 16);
    constexpr int MH   = MREP / 2;
    constexpr int CHA  = BM * 8 / NT;
    constexpr int CHB  = BN * 8 / NT;

    __shared__ u16 As[2][BM * 64];
    __shared__ u16 Bs[2][BN * 64];

    const int orig = blockIdx.x;
    const int xcd  = orig & 7, lo = orig >> 3;
    const int swz  = (xcd < r ? xcd * (q + 1) : r * (q + 1) + (xcd - r) * q) + lo;
    const int bx   = swz % gx;
    const int tmp2 = swz / gx;
    const int by   = tmp2 % gy;
    const int bz   = tmp2 / gy;

    const u16* Ab = A + (long)bz * sA + (long)by * BM * lda;
    const u16* Bb = B + (long)bz * sB + (long)bx * BN * ldb;

    const int tid = threadIdx.x;
    const int l   = tid & 63;
    const int wid = tid >> 6;
    const int wr  = (wid / WN) * (MREP * 16);
    const int wc  = (wid % WN) * (NREP * 16);
    const int lr  = l & 15;
    const int shi = l >> 4;

    auto stage = [&](int buf, int k0) {
#pragma unroll
        for (int i = 0; i < CHA; ++i) {
            const int c = tid + i * NT, row = c >> 3, p = c & 7;
            gload_lds16(Ab + (long)row * lda + k0 + ((p ^ (row & 7)) << 3),
                        &As[buf][c << 3]);
        }
#pragma unroll
        for (int i = 0; i < CHB; ++i) {
            const int c = tid + i * NT, row = c >> 3, p = c & 7;
            gload_lds16(Bb + (long)row * ldb + k0 + ((p ^ (row & 7)) << 3),
                        &Bs[buf][c << 3]);
        }
    };
    auto rdA = [&](int buf, int m, int ks) -> bf16x8 {
        const int row = wr + m * 16 + lr, slot = ks * 4 + shi;
        return *(const bf16x8*)&As[buf][row * 64 + ((slot ^ (row & 7)) << 3)];
    };
    auto rdB = [&](int buf, int n, int ks) -> bf16x8 {
        const int row = wc + n * 16 + lr, slot = ks * 4 + shi;
        return *(const bf16x8*)&Bs[buf][row * 64 + ((slot ^ (row & 7)) << 3)];
    };

    f32x4 acc[MREP][NREP] = {};
    const int nk = K / 64;

    stage(0, 0);
    stage(1, 64);
    asm volatile("s_waitcnt vmcnt(8)" ::: "memory");
    __builtin_amdgcn_sched_barrier(0);
    __builtin_amdgcn_s_barrier();

    int cur = 0;
    for (int t = 0; t < nk; ++t) {
        bf16x8 bfr[NREP][2];
#pragma unroll
        for (int n = 0; n < NREP; ++n) {
            bfr[n][0] = rdB(cur, n, 0);
            bfr[n][1] = rdB(cur, n, 1);
        }
        bf16x8 af[MH][2];
#pragma unroll
        for (int m = 0; m < MH; ++m) {
            af[m][0] = rdA(cur, m, 0);
            af[m][1] = rdA(cur, m, 1);
        }
        __builtin_amdgcn_s_setprio(1);
#pragma unroll
        for (int m = 0; m < MH; ++m)
#pragma unroll
            for (int n = 0; n < NREP; ++n) {
                acc[m][n] = __builtin_amdgcn_mfma_f32_16x16x32_bf16(
                    af[m][0], bfr[n][0], acc[m][n], 0, 0, 0);
                acc[m][n] = __builtin_amdgcn_mfma_f32_16x16x32_bf16(
                    af[m][1], bfr[n][1], acc[m][n], 0, 0, 0);
            }
        __builtin_amdgcn_s_setprio(0);

        bf16x8 ah[MH][2];
#pragma unroll
        for (int m = 0; m < MH; ++m) {
            ah[m][0] = rdA(cur, MH + m, 0);
            ah[m][1] = rdA(cur, MH + m, 1);
        }
        asm volatile("s_waitcnt lgkmcnt(0)" ::: "memory");
        __builtin_amdgcn_sched_barrier(0);
        __builtin_amdgcn_s_barrier();
        if (t + 2 < nk) stage(cur, (t + 2) * 64);
        __builtin_amdgcn_s_setprio(1);
#pragma unroll
        for (int m = 0; m < MH; ++m)
#pragma unroll
            for (int n = 0; n < NREP; ++n) {
                acc[MH + m][n] = __builtin_amdgcn_mfma_f32_16x16x32_bf16(
                    ah[m][0], bfr[n][0], acc[MH + m][n], 0, 0, 0);
                acc[MH + m][n] = __builtin_amdgcn_mfma_f32_16x16x32_bf16(
                    ah[m][1], bfr[n][1], acc[MH + m][n], 0, 0, 0);
            }
        __builtin_amdgcn_s_setprio(0);
        if (t + 2 < nk) {
            asm volatile("s_waitcnt vmcnt(8)" ::: "memory");
        } else {
            asm volatile("s_waitcnt vmcnt(0)" ::: "memory");
        }
        __builtin_amdgcn_sched_barrier(0);
        __builtin_amdgcn_s_barrier();
        cur ^= 1;
    }

    TC*        Cb = C + (long)bz * sC;
    const long rB = (long)by * BM + wr + (l >> 4) * 4;
    const long cB = (long)bx * BN + wc + lr;
#pragma unroll
    for (int m = 0; m < MREP; ++m)
#pragma unroll
        for (int n = 0; n < NREP; ++n)
#pragma unroll
            for (int j = 0; j < 4; ++j)
                store_c(&Cb[(rB + m * 16 + j) * ldc + cB + n * 16],
                        acc[m][n][j] * alpha);
}

template <int BM, int BN, int WM, int WN, typename TC>
static inline void run_gemm(hipStream_t s, const u16* A, const u16* B, TC* C,
                            int M, int N, int K, int lda, int ldb, int ldc,
                            long sA, long sB, long sC, float alpha, int batch)
{
    const int gx = N / BN, gy = M / BM;
    const int nwg = gx * gy * batch;
    gemm_pipe<BM, BN, WM, WN, TC><<<nwg, WM * WN * 64, 0, s>>>(
        A, B, C, K, lda, ldb, ldc, sA, sB, sC, alpha, gx, gy, nwg / 8, nwg % 8);
}

// ---------------------------------------------------------------------------
// f32 -> bf16 convert, 4 elems/thread
// ---------------------------------------------------------------------------
__global__ __launch_bounds__(256) void cvt_f32_bf16(
    const float* __restrict__ in, u16* __restrict__ out, long n)
{
    long i = ((long)blockIdx.x * 256 + threadIdx.x) * 4;
    if (i >= n) return;
    float4 v = *(const float4*)(in + i);
    u16x4 w = { f2bf(v.x), f2bf(v.y), f2bf(v.z), f2bf(v.w) };
    *(u16x4*)(out + i) = w;
}

__global__ __launch_bounds__(256) void cvt_w4(
    const float* __restrict__ w0, const float* __restrict__ w1,
    const float* __restrict__ w2, const float* __restrict__ w3,
    u16* __restrict__ out)
{
    const float* src = (blockIdx.y == 0) ? w0 : (blockIdx.y == 1) ? w1
                     : (blockIdx.y == 2) ? w2 : w3;
    long i = ((long)blockIdx.x * 256 + threadIdx.x) * 4;
    float4 v = *(const float4*)(src + i);
    u16x4 w = { f2bf(v.x), f2bf(v.y), f2bf(v.z), f2bf(v.w) };
    *(u16x4*)(out + (long)blockIdx.y * 1048576 + i) = w;
}

// ---------------------------------------------------------------------------
// V combine (logic gates on triplet projections) + transpose to Vt[b][o][t]
// ---------------------------------------------------------------------------
__global__ __launch_bounds__(256) void combine_v(
    const u16* __restrict__ vp, const int* __restrict__ ids,
    u16* __restrict__ Vt)
{
    __shared__ u16 tile[64][68];
    const int b  = blockIdx.z;
    const int t0 = blockIdx.x * 64;
    const int o0 = blockIdx.y * 64;
    const int tx = threadIdx.x;
    const int ty = threadIdx.y;

#pragma unroll
    for (int i = 0; i < 4; ++i) {
        const int  tloc = ty + i * 16;
        const int  t    = t0 + tloc;
        const long base = ((long)(b * 512 + t) * 3) * 1024 + o0 + tx * 4;
        const int  rel  = ids[(b * 512 + t) * 3];
        u16x4 r0 = *(const u16x4*)(vp + base);
        u16x4 r1 = *(const u16x4*)(vp + base + 1024);
        u16x4 r2 = *(const u16x4*)(vp + base + 2048);
#pragma unroll
        for (int c = 0; c < 4; ++c) {
            float vr = bf2f(r0[c]);
            float x1 = bf2f(r1[c]);
            float x2 = bf2f(r2[c]);
            float vf;
            switch (rel) {
                case 0:  vf = fminf(x1, x2);  break;
                case 1:  vf = fmaxf(x1, x2);  break;
                case 2:  vf = -x1;            break;
                case 3:  vf = fmaxf(-x1, x2); break;
                case 4:  vf = fabsf(x1 - x2); break;
                default: vf = vr;             break;
            }
            tile[tloc][tx * 4 + c] = f2bf(vf);
        }
    }
    __syncthreads();
#pragma unroll
    for (int j = 0; j < 4; ++j) {
        const int ol = ty + j * 16;
        u16x4 w;
#pragma unroll
        for (int c = 0; c < 4; ++c) w[c] = tile[tx * 4 + c][ol];
        *(u16x4*)(Vt + ((long)(b * 1024 + o0 + ol)) * 512 + t0 + tx * 4) = w;
    }
}

// ---------------------------------------------------------------------------
// Row softmax over 512 f32 scores -> bf16 probs. One wave per row.
// ---------------------------------------------------------------------------
__global__ __launch_bounds__(256) void softmax_rows(
    const float* __restrict__ S, u16* __restrict__ P)
{
    const int row = blockIdx.x * 4 + (threadIdx.x >> 6);
    const int l   = threadIdx.x & 63;
    const float4* src = (const float4*)(S + (long)row * 512);
    float4 a = src[l];
    float4 b = src[64 + l];

    float m = fmaxf(fmaxf(fmaxf(a.x, a.y), fmaxf(a.z, a.w)),
                    fmaxf(fmaxf(b.x, b.y), fmaxf(b.z, b.w)));
#pragma unroll
    for (int off = 32; off; off >>= 1) m = fmaxf(m, __shfl_xor(m, off));

    a.x = __expf(a.x - m); a.y = __expf(a.y - m);
    a.z = __expf(a.z - m); a.w = __expf(a.w - m);
    b.x = __expf(b.x - m); b.y = __expf(b.y - m);
    b.z = __expf(b.z - m); b.w = __expf(b.w - m);

    float s = a.x + a.y + a.z + a.w + b.x + b.y + b.z + b.w;
#pragma unroll
    for (int off = 32; off; off >>= 1) s += __shfl_xor(s, off);
    const float inv = 1.0f / s;

    u16x4 w0 = { f2bf(a.x * inv), f2bf(a.y * inv), f2bf(a.z * inv), f2bf(a.w * inv) };
    u16x4 w1 = { f2bf(b.x * inv), f2bf(b.y * inv), f2bf(b.z * inv), f2bf(b.w * inv) };
    u16x4* dst = (u16x4*)(P + (long)row * 512);
    dst[l]      = w0;
    dst[64 + l] = w1;
}

// ---------------------------------------------------------------------------
extern "C" void kernel_launch(void* const* d_in, const int* in_sizes, int n_in,
                              void* d_out, int out_size, void* d_ws, size_t ws_size,
                              hipStream_t stream)
{
    const float* hidden  = (const float*)d_in[0];
    const float* advisor = (const float*)d_in[1];
    const int*   ids     = (const int*)d_in[2];
    const float* Wq      = (const float*)d_in[3];
    const float* Wk      = (const float*)d_in[4];
    const float* Wv      = (const float*)d_in[5];
    const float* Wo      = (const float*)d_in[6];
    float*       out     = (float*)d_out;

    char* ws = (char*)d_ws;
    const long MB = 1L << 20;
    u16*   Wq_bf  = (u16*)(ws + 0 * MB);     // 2MB (Wk/Wv/Wo follow contiguously)
    u16*   Hbf    = (u16*)(ws + 8 * MB);     // 32MB  (dead after Q gemm)
    float* scores = (float*)(ws + 8 * MB);   // 32MB  (reuses Hbf)
    u16*   Abf    = (u16*)(ws + 40 * MB);    // 24MB  (dead after K/V gemms)
    u16*   P      = (u16*)(ws + 40 * MB);    // 16MB  (reuses Abf)
    u16*   Qbf    = (u16*)(ws + 64 * MB);    // 32MB  (dead after scores)
    u16*   ctx    = (u16*)(ws + 64 * MB);    // 32MB  (reuses Qbf)
    u16*   Kf     = (u16*)(ws + 96 * MB);    // 8MB
    u16*   Vt     = (u16*)(ws + 104 * MB);   // 8MB
    u16*   vp     = (u16*)(ws + 112 * MB);   // 24MB

    u16* Wk_bf = Wq_bf + 1048576;
    u16* Wv_bf = Wq_bf + 2097152;
    u16* Wo_bf = Wq_bf + 3145728;

    // 1) converts
    cvt_f32_bf16<<<16384, 256, 0, stream>>>(hidden,  Hbf, 16777216L);
    cvt_f32_bf16<<<12288, 256, 0, stream>>>(advisor, Abf, 12582912L);
    cvt_w4<<<dim3(1024, 4), 256, 0, stream>>>(Wq, Wk, Wv, Wo, Wq_bf);

    // 2) projections
    // Q = hidden @ Wq^T (16384 x 1024 x 1024)  — 8-phase
    run_gemm8<u16>(stream, Hbf, Wq_bf, Qbf, 16384, 1024, 1024,
                   1024, 1024, 1024, 1.0f);
    // K = trip0 @ Wk^T (4096 x 1024 x 1024), A row stride 3072 — 2-phase
    run_gemm<128, 128, 2, 2, u16>(stream, Abf, Wk_bf, Kf,
        4096, 1024, 1024, 3072, 1024, 1024, 0, 0, 0, 1.0f, 1);
    // Vproj = advisor @ Wv^T (12288 x 1024 x 1024) — 8-phase
    run_gemm8<u16>(stream, Abf, Wv_bf, vp, 12288, 1024, 1024,
                   1024, 1024, 1024, 1.0f);

    // 3) logic-gate combine + transpose -> Vt[b][o][t]
    combine_v<<<dim3(8, 16, 8), dim3(16, 16), 0, stream>>>(vp, ids, Vt);

    // 4) scores = Q @ K^T / 32  (batched 2048 x 512 x 1024), f32 — 2-phase
    run_gemm<128, 128, 2, 2, float>(stream, Qbf, Kf, scores,
        2048, 512, 1024, 1024, 1024, 512,
        2048L * 1024, 512L * 1024, 2048L * 512, 0.03125f, 8);

    // 5) softmax rows -> P bf16
    softmax_rows<<<4096, 256, 0, stream>>>(scores, P);

    // 6) ctx = P @ Vt^T (batched 2048 x 1024 x 512) — 2-phase
    run_gemm<128, 128, 2, 2, u16>(stream, P, Vt, ctx,
        2048, 1024, 512, 512, 512, 1024,
        2048L * 512, 1024L * 512, 2048L * 1024, 1.0f, 8);

    // 7) out = ctx @ Wo^T (16384 x 1024 x 1024) -> f32 — 8-phase
    run_gemm8<float>(stream, ctx, Wo_bf, out, 16384, 1024, 1024,
                     1024, 1024, 1024, 1.0f);
}

// Round 13
// 364.496 us; speedup vs baseline: 1.0074x; 1.0074x over previous
//
#include <hip/hip_runtime.h>
#include <hip/hip_bf16.h>

// ---------------------------------------------------------------------------
// AdvisorCrossAttention on MI355X (gfx950) — round 13 (resubmit of round 12:
// GPU acquisition timed out; k-outermost MFMA reorder still unmeasured)
// Single change vs round 11: MFMA issue order in all clusters is k-outermost
// (all k0 MFMAs across accumulators, then all k1) so consecutive instructions
// are independent — dependent pairs were back-to-back (measured ~15 cyc/MFMA
// effective vs ~4.85 µbench). Bitwise-identical accumulation order per acc.
// ---------------------------------------------------------------------------

typedef unsigned short u16;
typedef __attribute__((ext_vector_type(8))) short bf16x8;   // 8 bf16 = 4 VGPRs
typedef __attribute__((ext_vector_type(4))) float f32x4;    // MFMA acc
typedef __attribute__((ext_vector_type(4))) unsigned short u16x4;

__device__ __forceinline__ u16 f2bf(float f) {
    __hip_bfloat16 h = __float2bfloat16(f);
    return *reinterpret_cast<u16*>(&h);
}
__device__ __forceinline__ float bf2f(u16 u) {
    __hip_bfloat16 h;
    *reinterpret_cast<u16*>(&h) = u;
    return __bfloat162float(h);
}

__device__ __forceinline__ void gload_lds16(const u16* g, u16* l) {
    __builtin_amdgcn_global_load_lds(
        (const __attribute__((address_space(1))) void*)g,
        (__attribute__((address_space(3))) void*)l, 16, 0, 0);
}

__device__ __forceinline__ void store_c(float* p, float v) { *p = v; }
__device__ __forceinline__ void store_c(u16* p, float v)   { *p = f2bf(v); }

// ===========================================================================
// 8-phase 256x256 GEMM (batch=1): C[m,n] = sum_k A[m,k]*B[n,k]
// 8 waves (2M x 4N), per-wave 128x64 output, BK=64, LDS 128KB double-buffer.
// ===========================================================================
template <typename TC>
__global__ __launch_bounds__(512, 2) void gemm_8ph(
    const u16* __restrict__ A, const u16* __restrict__ B, TC* __restrict__ C,
    int K, int lda, int ldb, int ldc, float alpha, int gx, int q, int r)
{
    __shared__ u16 As[2][256 * 64];
    __shared__ u16 Bs[2][256 * 64];

    // T1: bijective XCD swizzle (m204)
    const int orig = blockIdx.x;
    const int xcd  = orig & 7, lo = orig >> 3;
    const int swz  = (xcd < r ? xcd * (q + 1) : r * (q + 1) + (xcd - r) * q) + lo;
    const int bx   = swz % gx;
    const int by   = swz / gx;

    const u16* Ab = A + (long)by * 256 * lda;
    const u16* Bb = B + (long)bx * 256 * ldb;

    const int tid = threadIdx.x;
    const int l   = tid & 63;
    const int wid = tid >> 6;
    const int wr  = (wid >> 2) * 128;   // wave M offset (2 groups)
    const int wc  = (wid & 3) * 64;     // wave N offset (4 groups)
    const int lr  = l & 15;
    const int shi = l >> 4;

    // stage full A (or B) K-tile: 2048 16B chunks / 512 threads = 4 loads.
    // linear LDS dest + inverse-swizzled global source (rule 21).
    auto stageA = [&](int buf, int k0) {
#pragma unroll
        for (int i = 0; i < 4; ++i) {
            const int c = tid + i * 512, row = c >> 3, p = c & 7;
            gload_lds16(Ab + (long)row * lda + k0 + ((p ^ (row & 7)) << 3),
                        &As[buf][c << 3]);
        }
    };
    auto stageB = [&](int buf, int k0) {
#pragma unroll
        for (int i = 0; i < 4; ++i) {
            const int c = tid + i * 512, row = c >> 3, p = c & 7;
            gload_lds16(Bb + (long)row * ldb + k0 + ((p ^ (row & 7)) << 3),
                        &Bs[buf][c << 3]);
        }
    };
    auto rdA = [&](int buf, int m, int ks) -> bf16x8 {
        const int row = wr + m * 16 + lr, slot = ks * 4 + shi;
        return *(const bf16x8*)&As[buf][row * 64 + ((slot ^ (row & 7)) << 3)];
    };
    auto rdB = [&](int buf, int n, int ks) -> bf16x8 {
        const int row = wc + n * 16 + lr, slot = ks * 4 + shi;
        return *(const bf16x8*)&Bs[buf][row * 64 + ((slot ^ (row & 7)) << 3)];
    };

    f32x4 acc[8][4] = {};
    const int nk = K / 64;

    // prologue: tiles 0 and 1 staged; wait tile 0 (8 of 16 loads retired)
    stageA(0, 0);  stageB(0, 0);
    stageA(1, 64); stageB(1, 64);
    asm volatile("s_waitcnt vmcnt(8)" ::: "memory");
    __builtin_amdgcn_sched_barrier(0);
    __builtin_amdgcn_s_barrier();

    for (int t = 0; t < nk; ++t) {
        const int  cur  = t & 1;
        const bool pre  = (t + 2 < nk);
        const int  k2   = (t + 2) * 64;
        bf16x8 af[4][2], bl[2][2], bh[2][2];

        // ---- phase 1: read A-low half + B-low half; MFMA (m0-3, n0-1) ----
#pragma unroll
        for (int m = 0; m < 4; ++m) { af[m][0] = rdA(cur, m, 0); af[m][1] = rdA(cur, m, 1); }
#pragma unroll
        for (int n = 0; n < 2; ++n) { bl[n][0] = rdB(cur, n, 0); bl[n][1] = rdB(cur, n, 1); }
        __builtin_amdgcn_s_barrier();
        asm volatile("s_waitcnt lgkmcnt(0)" ::: "memory");
        __builtin_amdgcn_sched_barrier(0);
        __builtin_amdgcn_s_setprio(1);
#pragma unroll
        for (int k = 0; k < 2; ++k)                 // k-outermost: indep issue
#pragma unroll
            for (int m = 0; m < 4; ++m)
#pragma unroll
                for (int n = 0; n < 2; ++n)
                    acc[m][n] = __builtin_amdgcn_mfma_f32_16x16x32_bf16(
                        af[m][k], bl[n][k], acc[m][n], 0, 0, 0);
        __builtin_amdgcn_s_setprio(0);
        __builtin_amdgcn_s_barrier();

        // ---- phase 2: read B-high half; MFMA (m0-3, n2-3) ----
#pragma unroll
        for (int n = 0; n < 2; ++n) { bh[n][0] = rdB(cur, 2 + n, 0); bh[n][1] = rdB(cur, 2 + n, 1); }
        __builtin_amdgcn_s_barrier();
        asm volatile("s_waitcnt lgkmcnt(0)" ::: "memory");
        __builtin_amdgcn_sched_barrier(0);
        __builtin_amdgcn_s_setprio(1);
#pragma unroll
        for (int k = 0; k < 2; ++k)
#pragma unroll
            for (int m = 0; m < 4; ++m)
#pragma unroll
                for (int n = 0; n < 2; ++n)
                    acc[m][2 + n] = __builtin_amdgcn_mfma_f32_16x16x32_bf16(
                        af[m][k], bh[n][k], acc[m][2 + n], 0, 0, 0);
        __builtin_amdgcn_s_setprio(0);
        __builtin_amdgcn_s_barrier();

        // ---- phase 3: read A-high half (overwrite af); stage B(t+2) into
        //      freed B buffer (all B reads done after phase 2); MFMA (m4-7, n2-3)
#pragma unroll
        for (int m = 0; m < 4; ++m) { af[m][0] = rdA(cur, 4 + m, 0); af[m][1] = rdA(cur, 4 + m, 1); }
        if (pre) stageB(cur, k2);
        __builtin_amdgcn_s_barrier();
        asm volatile("s_waitcnt lgkmcnt(0)" ::: "memory");
        __builtin_amdgcn_sched_barrier(0);
        __builtin_amdgcn_s_setprio(1);
#pragma unroll
        for (int k = 0; k < 2; ++k)
#pragma unroll
            for (int m = 0; m < 4; ++m)
#pragma unroll
                for (int n = 0; n < 2; ++n)
                    acc[4 + m][2 + n] = __builtin_amdgcn_mfma_f32_16x16x32_bf16(
                        af[m][k], bh[n][k], acc[4 + m][2 + n], 0, 0, 0);
        __builtin_amdgcn_s_setprio(0);
        __builtin_amdgcn_s_barrier();

        // ---- phase 4: stage A(t+2) (all A reads done after phase 3);
        //      MFMA (m4-7, n0-1); counted vmcnt before tile swap ----
        if (pre) stageA(cur, k2);
        __builtin_amdgcn_s_barrier();
        __builtin_amdgcn_s_setprio(1);
#pragma unroll
        for (int k = 0; k < 2; ++k)
#pragma unroll
            for (int m = 0; m < 4; ++m)
#pragma unroll
                for (int n = 0; n < 2; ++n)
                    acc[4 + m][n] = __builtin_amdgcn_mfma_f32_16x16x32_bf16(
                        af[m][k], bl[n][k], acc[4 + m][n], 0, 0, 0);
        __builtin_amdgcn_s_setprio(0);
        if (pre) { asm volatile("s_waitcnt vmcnt(8)" ::: "memory"); }
        else     { asm volatile("s_waitcnt vmcnt(0)" ::: "memory"); }
        __builtin_amdgcn_sched_barrier(0);
        __builtin_amdgcn_s_barrier();
    }

    // epilogue: D mapping col = l&15, row = (l>>4)*4 + j
    const long rB = (long)by * 256 + wr + (l >> 4) * 4;
    const long cB = (long)bx * 256 + wc + lr;
#pragma unroll
    for (int m = 0; m < 8; ++m)
#pragma unroll
        for (int n = 0; n < 4; ++n)
#pragma unroll
            for (int j = 0; j < 4; ++j)
                store_c(&C[(rB + m * 16 + j) * ldc + cB + n * 16],
                        acc[m][n][j] * alpha);
}

template <typename TC>
static inline void run_gemm8(hipStream_t s, const u16* A, const u16* B, TC* C,
                             int M, int N, int K, int lda, int ldb, int ldc,
                             float alpha)
{
    const int gx = N / 256, nwg = gx * (M / 256);
    gemm_8ph<TC><<<nwg, 512, 0, s>>>(A, B, C, K, lda, ldb, ldc, alpha,
                                     gx, nwg / 8, nwg % 8);
}

// ===========================================================================
// 2-phase 128x128 pipelined GEMM (4 waves) — measured: 0 bank conflicts.
// Used for small/batched GEMMs where 2 blocks/CU overlap the barriers.
// ===========================================================================
template <int BM, int BN, int WM, int WN, typename TC>
__global__ __launch_bounds__(WM*WN*64, 2) void gemm_pipe(
    const u16* __restrict__ A, const u16* __restrict__ B, TC* __restrict__ C,
    int K, int lda, int ldb, int ldc,
    long sA, long sB, long sC, float alpha,
    int gx, int gy, int q, int r)
{
    constexpr int NT   = WM * WN * 64;
    constexpr int MREP = BM / (WM * 16);
    constexpr int NREP = BN / (WN * 16);
    constexpr int MH   = MREP / 2;
    constexpr int CHA  = BM * 8 / NT;
    constexpr int CHB  = BN * 8 / NT;

    __shared__ u16 As[2][BM * 64];
    __shared__ u16 Bs[2][BN * 64];

    const int orig = blockIdx.x;
    const int xcd  = orig & 7, lo = orig >> 3;
    const int swz  = (xcd < r ? xcd * (q + 1) : r * (q + 1) + (xcd - r) * q) + lo;
    const int bx   = swz % gx;
    const int tmp2 = swz / gx;
    const int by   = tmp2 % gy;
    const int bz   = tmp2 / gy;

    const u16* Ab = A + (long)bz * sA + (long)by * BM * lda;
    const u16* Bb = B + (long)bz * sB + (long)bx * BN * ldb;

    const int tid = threadIdx.x;
    const int l   = tid & 63;
    const int wid = tid >> 6;
    const int wr  = (wid / WN) * (MREP * 16);
    const int wc  = (wid % WN) * (NREP * 16);
    const int lr  = l & 15;
    const int shi = l >> 4;

    auto stage = [&](int buf, int k0) {
#pragma unroll
        for (int i = 0; i < CHA; ++i) {
            const int c = tid + i * NT, row = c >> 3, p = c & 7;
            gload_lds16(Ab + (long)row * lda + k0 + ((p ^ (row & 7)) << 3),
                        &As[buf][c << 3]);
        }
#pragma unroll
        for (int i = 0; i < CHB; ++i) {
            const int c = tid + i * NT, row = c >> 3, p = c & 7;
            gload_lds16(Bb + (long)row * ldb + k0 + ((p ^ (row & 7)) << 3),
                        &Bs[buf][c << 3]);
        }
    };
    auto rdA = [&](int buf, int m, int ks) -> bf16x8 {
        const int row = wr + m * 16 + lr, slot = ks * 4 + shi;
        return *(const bf16x8*)&As[buf][row * 64 + ((slot ^ (row & 7)) << 3)];
    };
    auto rdB = [&](int buf, int n, int ks) -> bf16x8 {
        const int row = wc + n * 16 + lr, slot = ks * 4 + shi;
        return *(const bf16x8*)&Bs[buf][row * 64 + ((slot ^ (row & 7)) << 3)];
    };

    f32x4 acc[MREP][NREP] = {};
    const int nk = K / 64;

    stage(0, 0);
    stage(1, 64);
    asm volatile("s_waitcnt vmcnt(8)" ::: "memory");
    __builtin_amdgcn_sched_barrier(0);
    __builtin_amdgcn_s_barrier();

    int cur = 0;
    for (int t = 0; t < nk; ++t) {
        bf16x8 bfr[NREP][2];
#pragma unroll
        for (int n = 0; n < NREP; ++n) {
            bfr[n][0] = rdB(cur, n, 0);
            bfr[n][1] = rdB(cur, n, 1);
        }
        bf16x8 af[MH][2];
#pragma unroll
        for (int m = 0; m < MH; ++m) {
            af[m][0] = rdA(cur, m, 0);
            af[m][1] = rdA(cur, m, 1);
        }
        __builtin_amdgcn_s_setprio(1);
#pragma unroll
        for (int k = 0; k < 2; ++k)                 // k-outermost: indep issue
#pragma unroll
            for (int m = 0; m < MH; ++m)
#pragma unroll
                for (int n = 0; n < NREP; ++n)
                    acc[m][n] = __builtin_amdgcn_mfma_f32_16x16x32_bf16(
                        af[m][k], bfr[n][k], acc[m][n], 0, 0, 0);
        __builtin_amdgcn_s_setprio(0);

        bf16x8 ah[MH][2];
#pragma unroll
        for (int m = 0; m < MH; ++m) {
            ah[m][0] = rdA(cur, MH + m, 0);
            ah[m][1] = rdA(cur, MH + m, 1);
        }
        asm volatile("s_waitcnt lgkmcnt(0)" ::: "memory");
        __builtin_amdgcn_sched_barrier(0);
        __builtin_amdgcn_s_barrier();
        if (t + 2 < nk) stage(cur, (t + 2) * 64);
        __builtin_amdgcn_s_setprio(1);
#pragma unroll
        for (int k = 0; k < 2; ++k)
#pragma unroll
            for (int m = 0; m < MH; ++m)
#pragma unroll
                for (int n = 0; n < NREP; ++n)
                    acc[MH + m][n] = __builtin_amdgcn_mfma_f32_16x16x32_bf16(
                        ah[m][k], bfr[n][k], acc[MH + m][n], 0, 0, 0);
        __builtin_amdgcn_s_setprio(0);
        if (t + 2 < nk) {
            asm volatile("s_waitcnt vmcnt(8)" ::: "memory");
        } else {
            asm volatile("s_waitcnt vmcnt(0)" ::: "memory");
        }
        __builtin_amdgcn_sched_barrier(0);
        __builtin_amdgcn_s_barrier();
        cur ^= 1;
    }

    TC*        Cb = C + (long)bz * sC;
    const long rB = (long)by * BM + wr + (l >> 4) * 4;
    const long cB = (long)bx * BN + wc + lr;
#pragma unroll
    for (int m = 0; m < MREP; ++m)
#pragma unroll
        for (int n = 0; n < NREP; ++n)
#pragma unroll
            for (int j = 0; j < 4; ++j)
                store_c(&Cb[(rB + m * 16 + j) * ldc + cB + n * 16],
                        acc[m][n][j] * alpha);
}

template <int BM, int BN, int WM, int WN, typename TC>
static inline void run_gemm(hipStream_t s, const u16* A, const u16* B, TC* C,
                            int M, int N, int K, int lda, int ldb, int ldc,
                            long sA, long sB, long sC, float alpha, int batch)
{
    const int gx = N / BN, gy = M / BM;
    const int nwg = gx * gy * batch;
    gemm_pipe<BM, BN, WM, WN, TC><<<nwg, WM * WN * 64, 0, s>>>(
        A, B, C, K, lda, ldb, ldc, sA, sB, sC, alpha, gx, gy, nwg / 8, nwg % 8);
}

// ---------------------------------------------------------------------------
// f32 -> bf16 convert, 4 elems/thread
// ---------------------------------------------------------------------------
__global__ __launch_bounds__(256) void cvt_f32_bf16(
    const float* __restrict__ in, u16* __restrict__ out, long n)
{
    long i = ((long)blockIdx.x * 256 + threadIdx.x) * 4;
    if (i >= n) return;
    float4 v = *(const float4*)(in + i);
    u16x4 w = { f2bf(v.x), f2bf(v.y), f2bf(v.z), f2bf(v.w) };
    *(u16x4*)(out + i) = w;
}

__global__ __launch_bounds__(256) void cvt_w4(
    const float* __restrict__ w0, const float* __restrict__ w1,
    const float* __restrict__ w2, const float* __restrict__ w3,
    u16* __restrict__ out)
{
    const float* src = (blockIdx.y == 0) ? w0 : (blockIdx.y == 1) ? w1
                     : (blockIdx.y == 2) ? w2 : w3;
    long i = ((long)blockIdx.x * 256 + threadIdx.x) * 4;
    float4 v = *(const float4*)(src + i);
    u16x4 w = { f2bf(v.x), f2bf(v.y), f2bf(v.z), f2bf(v.w) };
    *(u16x4*)(out + (long)blockIdx.y * 1048576 + i) = w;
}

// ---------------------------------------------------------------------------
// V combine (logic gates on triplet projections) + transpose to Vt[b][o][t]
// ---------------------------------------------------------------------------
__global__ __launch_bounds__(256) void combine_v(
    const u16* __restrict__ vp, const int* __restrict__ ids,
    u16* __restrict__ Vt)
{
    __shared__ u16 tile[64][68];
    const int b  = blockIdx.z;
    const int t0 = blockIdx.x * 64;
    const int o0 = blockIdx.y * 64;
    const int tx = threadIdx.x;
    const int ty = threadIdx.y;

#pragma unroll
    for (int i = 0; i < 4; ++i) {
        const int  tloc = ty + i * 16;
        const int  t    = t0 + tloc;
        const long base = ((long)(b * 512 + t) * 3) * 1024 + o0 + tx * 4;
        const int  rel  = ids[(b * 512 + t) * 3];
        u16x4 r0 = *(const u16x4*)(vp + base);
        u16x4 r1 = *(const u16x4*)(vp + base + 1024);
        u16x4 r2 = *(const u16x4*)(vp + base + 2048);
#pragma unroll
        for (int c = 0; c < 4; ++c) {
            float vr = bf2f(r0[c]);
            float x1 = bf2f(r1[c]);
            float x2 = bf2f(r2[c]);
            float vf;
            switch (rel) {
                case 0:  vf = fminf(x1, x2);  break;
                case 1:  vf = fmaxf(x1, x2);  break;
                case 2:  vf = -x1;            break;
                case 3:  vf = fmaxf(-x1, x2); break;
                case 4:  vf = fabsf(x1 - x2); break;
                default: vf = vr;             break;
            }
            tile[tloc][tx * 4 + c] = f2bf(vf);
        }
    }
    __syncthreads();
#pragma unroll
    for (int j = 0; j < 4; ++j) {
        const int ol = ty + j * 16;
        u16x4 w;
#pragma unroll
        for (int c = 0; c < 4; ++c) w[c] = tile[tx * 4 + c][ol];
        *(u16x4*)(Vt + ((long)(b * 1024 + o0 + ol)) * 512 + t0 + tx * 4) = w;
    }
}

// ---------------------------------------------------------------------------
// Row softmax over 512 f32 scores -> bf16 probs. One wave per row.
// ---------------------------------------------------------------------------
__global__ __launch_bounds__(256) void softmax_rows(
    const float* __restrict__ S, u16* __restrict__ P)
{
    const int row = blockIdx.x * 4 + (threadIdx.x >> 6);
    const int l   = threadIdx.x & 63;
    const float4* src = (const float4*)(S + (long)row * 512);
    float4 a = src[l];
    float4 b = src[64 + l];

    float m = fmaxf(fmaxf(fmaxf(a.x, a.y), fmaxf(a.z, a.w)),
                    fmaxf(fmaxf(b.x, b.y), fmaxf(b.z, b.w)));
#pragma unroll
    for (int off = 32; off; off >>= 1) m = fmaxf(m, __shfl_xor(m, off));

    a.x = __expf(a.x - m); a.y = __expf(a.y - m);
    a.z = __expf(a.z - m); a.w = __expf(a.w - m);
    b.x = __expf(b.x - m); b.y = __expf(b.y - m);
    b.z = __expf(b.z - m); b.w = __expf(b.w - m);

    float s = a.x + a.y + a.z + a.w + b.x + b.y + b.z + b.w;
#pragma unroll
    for (int off = 32; off; off >>= 1) s += __shfl_xor(s, off);
    const float inv = 1.0f / s;

    u16x4 w0 = { f2bf(a.x * inv), f2bf(a.y * inv), f2bf(a.z * inv), f2bf(a.w * inv) };
    u16x4 w1 = { f2bf(b.x * inv), f2bf(b.y * inv), f2bf(b.z * inv), f2bf(b.w * inv) };
    u16x4* dst = (u16x4*)(P + (long)row * 512);
    dst[l]      = w0;
    dst[64 + l] = w1;
}

// ---------------------------------------------------------------------------
extern "C" void kernel_launch(void* const* d_in, const int* in_sizes, int n_in,
                              void* d_out, int out_size, void* d_ws, size_t ws_size,
                              hipStream_t stream)
{
    const float* hidden  = (const float*)d_in[0];
    const float* advisor = (const float*)d_in[1];
    const int*   ids     = (const int*)d_in[2];
    const float* Wq      = (const float*)d_in[3];
    const float* Wk      = (const float*)d_in[4];
    const float* Wv      = (const float*)d_in[5];
    const float* Wo      = (const float*)d_in[6];
    float*       out     = (float*)d_out;

    char* ws = (char*)d_ws;
    const long MB = 1L << 20;
    u16*   Wq_bf  = (u16*)(ws + 0 * MB);     // 2MB (Wk/Wv/Wo follow contiguously)
    u16*   Hbf    = (u16*)(ws + 8 * MB);     // 32MB  (dead after Q gemm)
    float* scores = (float*)(ws + 8 * MB);   // 32MB  (reuses Hbf)
    u16*   Abf    = (u16*)(ws + 40 * MB);    // 24MB  (dead after K/V gemms)
    u16*   P      = (u16*)(ws + 40 * MB);    // 16MB  (reuses Abf)
    u16*   Qbf    = (u16*)(ws + 64 * MB);    // 32MB  (dead after scores)
    u16*   ctx    = (u16*)(ws + 64 * MB);    // 32MB  (reuses Qbf)
    u16*   Kf     = (u16*)(ws + 96 * MB);    // 8MB
    u16*   Vt     = (u16*)(ws + 104 * MB);   // 8MB
    u16*   vp     = (u16*)(ws + 112 * MB);   // 24MB

    u16* Wk_bf = Wq_bf + 1048576;
    u16* Wv_bf = Wq_bf + 2097152;
    u16* Wo_bf = Wq_bf + 3145728;

    // 1) converts
    cvt_f32_bf16<<<16384, 256, 0, stream>>>(hidden,  Hbf, 16777216L);
    cvt_f32_bf16<<<12288, 256, 0, stream>>>(advisor, Abf, 12582912L);
    cvt_w4<<<dim3(1024, 4), 256, 0, stream>>>(Wq, Wk, Wv, Wo, Wq_bf);

    // 2) projections
    // Q = hidden @ Wq^T (16384 x 1024 x 1024)  — 8-phase
    run_gemm8<u16>(stream, Hbf, Wq_bf, Qbf, 16384, 1024, 1024,
                   1024, 1024, 1024, 1.0f);
    // K = trip0 @ Wk^T (4096 x 1024 x 1024), A row stride 3072 — 2-phase
    run_gemm<128, 128, 2, 2, u16>(stream, Abf, Wk_bf, Kf,
        4096, 1024, 1024, 3072, 1024, 1024, 0, 0, 0, 1.0f, 1);
    // Vproj = advisor @ Wv^T (12288 x 1024 x 1024) — 8-phase
    run_gemm8<u16>(stream, Abf, Wv_bf, vp, 12288, 1024, 1024,
                   1024, 1024, 1024, 1.0f);

    // 3) logic-gate combine + transpose -> Vt[b][o][t]
    combine_v<<<dim3(8, 16, 8), dim3(16, 16), 0, stream>>>(vp, ids, Vt);

    // 4) scores = Q @ K^T / 32  (batched 2048 x 512 x 1024), f32 — 2-phase
    run_gemm<128, 128, 2, 2, float>(stream, Qbf, Kf, scores,
        2048, 512, 1024, 1024, 1024, 512,
        2048L * 1024, 512L * 1024, 2048L * 512, 0.03125f, 8);

    // 5) softmax rows -> P bf16
    softmax_rows<<<4096, 256, 0, stream>>>(scores, P);

    // 6) ctx = P @ Vt^T (batched 2048 x 1024 x 512) — 2-phase
    run_gemm<128, 128, 2, 2, u16>(stream, P, Vt, ctx,
        2048, 1024, 512, 512, 512, 1024,
        2048L * 512, 1024L * 512, 2048L * 1024, 1.0f, 8);

    // 7) out = ctx @ Wo^T (16384 x 1024 x 1024) -> f32 — 8-phase
    run_gemm8<float>(stream, ctx, Wo_bf, out, 16384, 1024, 1024,
                     1024, 1024, 1024, 1.0f);
}